// Round 1
// baseline (515.148 us; speedup 1.0000x reference)
//
#include <hip/hip_runtime.h>

typedef __attribute__((ext_vector_type(8))) short bf16x8;   // 8 bf16 = 4 VGPR
typedef __attribute__((ext_vector_type(4))) float f32x4;

#define RT 128          // rows per block
#define NB (262144 / RT)

static_assert(262144 % RT == 0, "rows must divide");

__device__ __forceinline__ short f2bf(float f) {
  union { float f; unsigned u; } x; x.f = f;
  unsigned r = x.u + 0x7FFFu + ((x.u >> 16) & 1u);   // RNE
  return (short)(r >> 16);
}

__global__ __launch_bounds__(512, 2) void rrsep(
    const float* __restrict__ y_real, const float* __restrict__ y_imag,
    const float* __restrict__ W1, const float* __restrict__ b1,
    const float* __restrict__ W2, const float* __restrict__ b2,
    const float* __restrict__ W3, const float* __restrict__ b3,
    float* __restrict__ out)
{
  // x_lds: bf16 state [p][row][24], contiguous (k-pad 24..31 reads spill into
  // next row = finite garbage, killed by zeroed weight pads; +8 tail zeroed).
  __shared__ unsigned short x_lds[4 * RT * 24 + 8];
  __shared__ unsigned short h_lds[8][16 * 64];   // per-wave H^T bounce, XOR-swizzled
  __shared__ float o_lds[4][2][RT][12];          // per-stage outputs (f32)
  __shared__ float y_lds[2][RT][12];             // normalized yr, yi
  __shared__ float e_lds[RT];

  const int tid  = (int)threadIdx.x;
  const int lane = tid & 63;
  const int w    = tid >> 6;        // wave 0..7
  const int p    = w >> 1;          // port
  const int c    = w & 1;           // channel
  const int g    = lane >> 4;       // lane group 0..3
  const int q    = lane & 15;       // lane-in-group
  const long r0  = (long)blockIdx.x * RT;

  // ---------------- prologue: e, normalized y, initial x ----------------
  if (tid < 8) x_lds[4 * RT * 24 + tid] = 0;
  for (int r = tid; r < RT; r += 512) {
    float yr[12], yi[12]; float acc = 0.f;
    #pragma unroll
    for (int l = 0; l < 12; ++l) {
      yr[l] = y_real[(r0 + r) * 12 + l];
      yi[l] = y_imag[(r0 + r) * 12 + l];
      acc += yr[l] * yr[l] + yi[l] * yi[l];
    }
    float e   = sqrtf(acc * (1.f / 12.f));
    float inv = 1.f / (e + 1e-8f);
    e_lds[r] = e;
    #pragma unroll
    for (int l = 0; l < 12; ++l) {
      y_lds[0][r][l] = yr[l] * inv;
      y_lds[1][r][l] = yi[l] * inv;
    }
  }
  __syncthreads();
  for (int idx = tid; idx < 4 * RT * 24; idx += 512) {
    int f  = idx % 24;
    int rp = idx / 24;
    int r  = rp % RT;
    float v = (f < 12) ? y_lds[0][r][f] : y_lds[1][r][f - 12];
    x_lds[idx] = (unsigned short)f2bf(v);
  }
  __syncthreads();

  unsigned short* hbase = h_lds[w];
  const int swz = (q & 7) << 4;

  for (int s = 0; s < 3; ++s) {
    const int pc = (s * 4 + p) * 2 + c;
    const float* W1g = W1 + pc * 24 * 64;
    const float* b1g = b1 + pc * 64;
    const float* W2g = W2 + pc * 64 * 64;
    const float* b2g = b2 + pc * 64;
    const float* W3g = W3 + pc * 64 * 12;
    const float* b3g = b3 + pc * 12;

    // ---- weight / bias fragments (A-operand = W^T, weight-stationary) ----
    // A-frag layout: lane holds A[m = 16*mt + q][k = 32*kt + 8*g + j], A[m][k] = W[k][m]
    bf16x8 w1f[4], w2f[2][4], w3f[2];
    f32x4 b1f[4], b2f[4], b3f;
    #pragma unroll
    for (int mt = 0; mt < 4; ++mt) {
      bf16x8 a;
      #pragma unroll
      for (int j = 0; j < 8; ++j) {
        int k = 8 * g + j;
        a[j] = (k < 24) ? f2bf(W1g[k * 64 + 16 * mt + q]) : (short)0;  // zero K-pad
      }
      w1f[mt] = a;
      #pragma unroll
      for (int kt = 0; kt < 2; ++kt) {
        bf16x8 a2;
        #pragma unroll
        for (int j = 0; j < 8; ++j)
          a2[j] = f2bf(W2g[(32 * kt + 8 * g + j) * 64 + 16 * mt + q]);
        w2f[kt][mt] = a2;
      }
      f32x4 bv1, bv2;
      #pragma unroll
      for (int r = 0; r < 4; ++r) {            // C-layout: row m = 16*mt + 4*g + r
        bv1[r] = b1g[16 * mt + 4 * g + r];
        bv2[r] = b2g[16 * mt + 4 * g + r];
      }
      b1f[mt] = bv1; b2f[mt] = bv2;
    }
    #pragma unroll
    for (int kt = 0; kt < 2; ++kt) {
      bf16x8 a3;
      #pragma unroll
      for (int j = 0; j < 8; ++j)
        a3[j] = (q < 12) ? f2bf(W3g[(32 * kt + 8 * g + j) * 12 + q]) : (short)0;  // zero M-pad
      w3f[kt] = a3;
    }
    #pragma unroll
    for (int r = 0; r < 4; ++r) {
      int m = 4 * g + r;
      b3f[r] = (m < 12) ? b3g[m] : 0.f;
    }

    // ---------------- main: 16-row chunks ----------------
    for (int ch = 0; ch < RT / 16; ++ch) {
      const int rr = ch * 16 + q;    // this lane's data row (N index)

      // mm1: H1^T = W1^T · X^T  (B-frag = contiguous ds_read_b128 of x row)
      bf16x8 xb = *(const bf16x8*)&x_lds[(p * RT + rr) * 24 + 8 * g];
      f32x4 c1[4];
      #pragma unroll
      for (int mt = 0; mt < 4; ++mt)
        c1[mt] = __builtin_amdgcn_mfma_f32_16x16x32_bf16(w1f[mt], xb, b1f[mt], 0, 0, 0);

      // relu + pack -> h_lds (swizzled); lane writes feats 16*mt+4*g..+3 at row q
      #pragma unroll
      for (int mt = 0; mt < 4; ++mt) {
        unsigned lo = (unsigned)(unsigned short)f2bf(fmaxf(c1[mt][0], 0.f)) |
                      ((unsigned)(unsigned short)f2bf(fmaxf(c1[mt][1], 0.f)) << 16);
        unsigned hi = (unsigned)(unsigned short)f2bf(fmaxf(c1[mt][2], 0.f)) |
                      ((unsigned)(unsigned short)f2bf(fmaxf(c1[mt][3], 0.f)) << 16);
        unsigned long long v = (unsigned long long)lo | ((unsigned long long)hi << 32);
        int off = (q * 128 + 32 * mt + 8 * g) ^ swz;
        *(unsigned long long*)((char*)hbase + off) = v;
      }

      // mm2: H2^T = W2^T · H1^T
      f32x4 c2[4];
      #pragma unroll
      for (int mt = 0; mt < 4; ++mt) c2[mt] = b2f[mt];
      #pragma unroll
      for (int kt = 0; kt < 2; ++kt) {
        int off = (q * 128 + 16 * g + 64 * kt) ^ swz;
        bf16x8 hb = *(const bf16x8*)((const char*)hbase + off);
        #pragma unroll
        for (int mt = 0; mt < 4; ++mt)
          c2[mt] = __builtin_amdgcn_mfma_f32_16x16x32_bf16(w2f[kt][mt], hb, c2[mt], 0, 0, 0);
      }

      // relu + pack -> h_lds (reuse; wave-private, DS ops are in-order)
      #pragma unroll
      for (int mt = 0; mt < 4; ++mt) {
        unsigned lo = (unsigned)(unsigned short)f2bf(fmaxf(c2[mt][0], 0.f)) |
                      ((unsigned)(unsigned short)f2bf(fmaxf(c2[mt][1], 0.f)) << 16);
        unsigned hi = (unsigned)(unsigned short)f2bf(fmaxf(c2[mt][2], 0.f)) |
                      ((unsigned)(unsigned short)f2bf(fmaxf(c2[mt][3], 0.f)) << 16);
        unsigned long long v = (unsigned long long)lo | ((unsigned long long)hi << 32);
        int off = (q * 128 + 32 * mt + 8 * g) ^ swz;
        *(unsigned long long*)((char*)hbase + off) = v;
      }

      // mm3: O^T = W3^T · H2^T  (M padded 12->16, pad rows zero)
      f32x4 c3 = b3f;
      #pragma unroll
      for (int kt = 0; kt < 2; ++kt) {
        int off = (q * 128 + 16 * g + 64 * kt) ^ swz;
        bf16x8 hb = *(const bf16x8*)((const char*)hbase + off);
        c3 = __builtin_amdgcn_mfma_f32_16x16x32_bf16(w3f[kt], hb, c3, 0, 0, 0);
      }
      if (g < 3) *(f32x4*)&o_lds[p][c][rr][4 * g] = c3;   // m = 4g..4g+3 < 12
    }
    __syncthreads();

    // ---------------- residual combine ----------------
    if (s < 2) {
      for (int idx = tid; idx < RT * 12; idx += 512) {
        int r = idx / 12, l = idx % 12;
        float sR = 0.f, sI = 0.f;
        #pragma unroll
        for (int pp = 0; pp < 4; ++pp) { sR += o_lds[pp][0][r][l]; sI += o_lds[pp][1][r][l]; }
        float rres = y_lds[0][r][l] - sR;
        float ires = y_lds[1][r][l] - sI;
        #pragma unroll
        for (int pp = 0; pp < 4; ++pp) {
          x_lds[(pp * RT + r) * 24 + l]      = (unsigned short)f2bf(o_lds[pp][0][r][l] + rres);
          x_lds[(pp * RT + r) * 24 + 12 + l] = (unsigned short)f2bf(o_lds[pp][1][r][l] + ires);
        }
      }
    } else {
      // residual into y_lds, then coalesced float4 output: out[b][p][l][c] * e
      for (int idx = tid; idx < RT * 12; idx += 512) {
        int r = idx / 12, l = idx % 12;
        float sR = 0.f, sI = 0.f;
        #pragma unroll
        for (int pp = 0; pp < 4; ++pp) { sR += o_lds[pp][0][r][l]; sI += o_lds[pp][1][r][l]; }
        y_lds[0][r][l] -= sR;
        y_lds[1][r][l] -= sI;
      }
      __syncthreads();
      const int r  = tid >> 2;      // 512 threads = 128 rows x 4 ports
      const int pp = tid & 3;
      const float e = e_lds[r];
      float vals[24];
      #pragma unroll
      for (int k = 0; k < 24; ++k) {
        int l = k >> 1, cc = k & 1;
        vals[k] = (o_lds[pp][cc][r][l] + y_lds[cc][r][l]) * e;
      }
      float* ob = out + r0 * 96 + (long)tid * 24;
      #pragma unroll
      for (int v4 = 0; v4 < 6; ++v4) {
        f32x4 t;
        t[0] = vals[4 * v4 + 0]; t[1] = vals[4 * v4 + 1];
        t[2] = vals[4 * v4 + 2]; t[3] = vals[4 * v4 + 3];
        *(f32x4*)(ob + 4 * v4) = t;
      }
    }
    __syncthreads();
  }
}

extern "C" void kernel_launch(void* const* d_in, const int* in_sizes, int n_in,
                              void* d_out, int out_size, void* d_ws, size_t ws_size,
                              hipStream_t stream) {
  const float* y_real = (const float*)d_in[0];
  const float* y_imag = (const float*)d_in[1];
  const float* W1 = (const float*)d_in[2];
  const float* b1 = (const float*)d_in[3];
  const float* W2 = (const float*)d_in[4];
  const float* b2 = (const float*)d_in[5];
  const float* W3 = (const float*)d_in[6];
  const float* b3 = (const float*)d_in[7];
  float* out = (float*)d_out;

  hipLaunchKernelGGL(rrsep, dim3(NB), dim3(512), 0, stream,
                     y_real, y_imag, W1, b1, W2, b2, W3, b3, out);
}

// Round 3
// 465.373 us; speedup vs baseline: 1.1070x; 1.1070x over previous
//
#include <hip/hip_runtime.h>
#include <hip/hip_bf16.h>

typedef __attribute__((ext_vector_type(8))) short bf16x8;
typedef __attribute__((ext_vector_type(4))) float f32x4;
typedef __attribute__((ext_vector_type(16))) float f32x16;
typedef __attribute__((ext_vector_type(4))) unsigned int u32x4;
typedef unsigned long long ull;

#define RT 128
#define NB (262144 / RT)
#define XSTR 40   // x row stride in bf16 elems (aug pair at 24/25, zeros 26..31)

// LDS byte offsets
#define X_OFF 0          // x: [4][128][XSTR] bf16  = 40960 B
#define O_OFF 40960      // o: [4][2][129][12] bf16 = 24768 B
#define Y_OFF 65728      // y: [2][128][12] bf16    =  6144 B
#define E_OFF 71872      // e: [128] f32            =   512 B
#define SMEM_BYTES 72384

// Defined-order bf16 pair pack: lo -> low 16 bits, hi -> high 16 bits.
__device__ __forceinline__ unsigned pk2(float lo, float hi) {
  union { __hip_bfloat162 h; unsigned u; } U;
  U.h = __float22bfloat162_rn(make_float2(lo, hi));
  return U.u;
}
__device__ __forceinline__ void unp4(ull v, float* d) {
  unsigned a = (unsigned)v, b = (unsigned)(v >> 32);
  union { unsigned u; float f; } x;
  x.u = a << 16;         d[0] = x.f;
  x.u = a & 0xffff0000u; d[1] = x.f;
  x.u = b << 16;         d[2] = x.f;
  x.u = b & 0xffff0000u; d[3] = x.f;
}
__device__ __forceinline__ bf16x8 mkfrag(unsigned w0, unsigned w1, unsigned w2, unsigned w3) {
  union { bf16x8 v; unsigned u[4]; } U;
  U.u[0] = w0; U.u[1] = w1; U.u[2] = w2; U.u[3] = w3;
  return U.v;
}
__device__ __forceinline__ f32x16 mfma32(bf16x8 a, bf16x8 b, f32x16 c) {
  return __builtin_amdgcn_mfma_f32_32x32x16_bf16(a, b, c, 0, 0, 0);
}

__global__ __launch_bounds__(512, 2) void rrsep(
    const float* __restrict__ y_real, const float* __restrict__ y_imag,
    const float* __restrict__ W1, const float* __restrict__ b1,
    const float* __restrict__ W2, const float* __restrict__ b2,
    const float* __restrict__ W3, const float* __restrict__ b3,
    float* __restrict__ out)
{
  __shared__ __align__(16) char smem[SMEM_BYTES];
  unsigned short* xs = (unsigned short*)(smem + X_OFF);
  unsigned short* os = (unsigned short*)(smem + O_OFF);
  unsigned short* ys = (unsigned short*)(smem + Y_OFF);
  float* es = (float*)(smem + E_OFF);

  const int tid  = (int)threadIdx.x;
  const int lane = tid & 63;
  const int w    = tid >> 6;     // wave 0..7
  const int p    = w >> 1;       // port
  const int c    = w & 1;        // channel
  const int n    = lane & 31;    // data column / weight m-lane
  const int h    = lane >> 5;    // lane half
  const long r0  = (long)blockIdx.x * RT;

  // ---------------- prologue: coalesced load, normalize, init x ----------------
  {
    float* stg = (float*)smem;   // overlays x region before its first use
    if (tid < 384) {
      ((f32x4*)stg)[tid]          = ((const f32x4*)(y_real + r0 * 12))[tid];
      ((f32x4*)(stg + 1536))[tid] = ((const f32x4*)(y_imag + r0 * 12))[tid];
    }
    __syncthreads();
    float yv[24]; float ev = 0.f, inv = 0.f;
    if (tid < RT) {
      float acc = 0.f;
      #pragma unroll
      for (int l = 0; l < 12; ++l) {
        yv[l]      = stg[tid * 12 + l];
        yv[12 + l] = stg[1536 + tid * 12 + l];
        acc += yv[l] * yv[l] + yv[12 + l] * yv[12 + l];
      }
      ev  = sqrtf(acc * (1.f / 12.f));
      inv = 1.f / (ev + 1e-8f);
    }
    __syncthreads();   // all slab reads done before x overwrites the region
    if (tid < RT) {
      es[tid] = ev;
      unsigned pkw[12];
      #pragma unroll
      for (int j = 0; j < 12; ++j) pkw[j] = pk2(yv[2*j] * inv, yv[2*j+1] * inv);
      ull* yr0 = (ull*)(ys + (0 * RT + tid) * 12);
      yr0[0] = (ull)pkw[0] | ((ull)pkw[1] << 32);
      yr0[1] = (ull)pkw[2] | ((ull)pkw[3] << 32);
      yr0[2] = (ull)pkw[4] | ((ull)pkw[5] << 32);
      ull* yr1 = (ull*)(ys + (1 * RT + tid) * 12);
      yr1[0] = (ull)pkw[6]  | ((ull)pkw[7]  << 32);
      yr1[1] = (ull)pkw[8]  | ((ull)pkw[9]  << 32);
      yr1[2] = (ull)pkw[10] | ((ull)pkw[11] << 32);
      #pragma unroll
      for (int p2 = 0; p2 < 4; ++p2) {
        u32x4* xr = (u32x4*)(xs + (p2 * RT + tid) * XSTR);
        u32x4 t0; t0[0]=pkw[0]; t0[1]=pkw[1]; t0[2]=pkw[2]; t0[3]=pkw[3];
        u32x4 t1; t1[0]=pkw[4]; t1[1]=pkw[5]; t1[2]=pkw[6]; t1[3]=pkw[7];
        u32x4 t2; t2[0]=pkw[8]; t2[1]=pkw[9]; t2[2]=pkw[10]; t2[3]=pkw[11];
        u32x4 t3; t3[0]=pk2(1.f, 0.f); t3[1]=0u; t3[2]=0u; t3[3]=0u;  // aug x[24]=1, pad 25..31=0
        xr[0]=t0; xr[1]=t1; xr[2]=t2; xr[3]=t3;
      }
    }
    __syncthreads();
  }

  f32x16 z;
  #pragma unroll
  for (int i = 0; i < 16; ++i) z[i] = 0.f;

  #pragma unroll 1
  for (int s = 0; s < 3; ++s) {
    const int pc = (s * 4 + p) * 2 + c;
    const float* W1g = W1 + pc * 24 * 64;
    const float* b1g = b1 + pc * 64;
    const float* W2g = W2 + pc * 64 * 64;
    const float* b2g = b2 + pc * 64;
    const float* W3g = W3 + pc * 64 * 12;
    const float* b3g = b3 + pc * 12;

    // ---- mm1 A-frags: elem j (half h) <-> k = 16kt+8h+j; A[m][k] = W1[k][m], k24 = b1 ----
    bf16x8 w1f[2][2];
    #pragma unroll
    for (int mt = 0; mt < 2; ++mt)
      #pragma unroll
      for (int kt = 0; kt < 2; ++kt) {
        unsigned u[4];
        #pragma unroll
        for (int wq = 0; wq < 4; ++wq) {
          int k0 = 16*kt + 8*h + 2*wq, k1 = k0 + 1;
          int m  = 32*mt + n;
          float v0 = (k0 < 24) ? W1g[k0*64 + m] : ((k0 == 24) ? b1g[m] : 0.f);
          float v1 = (k1 < 24) ? W1g[k1*64 + m] : 0.f;   // k1 odd, never the aug slot
          u[wq] = pk2(v0, v1);
        }
        w1f[mt][kt] = mkfrag(u[0], u[1], u[2], u[3]);
      }

    // ---- mm2/mm3 A-frags with phi-permuted rows so the hop is register-contiguous ----
    // phi(kt,h,j) = 32*(kt>>1) + 16*(kt&1) + 8*(j>>2) + 4h + (j&3)
    //  == the feature held by C-reg c[kt>>1][8*(kt&1)+j] (C/D layout, HW-verified)
    bf16x8 w2f[2][4], w3f[4];
    #pragma unroll
    for (int mt = 0; mt < 2; ++mt)
      #pragma unroll
      for (int kt = 0; kt < 4; ++kt) {
        unsigned u[4];
        int m  = 32*mt + n;
        int rb = 32*(kt>>1) + 16*(kt&1) + 4*h;
        #pragma unroll
        for (int wq = 0; wq < 4; ++wq) {
          int r = rb + 8*(wq>>1) + 2*(wq&1);         // rows for elems 2wq, 2wq+1
          u[wq] = pk2(W2g[r*64 + m], W2g[(r+1)*64 + m]);
        }
        w2f[mt][kt] = mkfrag(u[0], u[1], u[2], u[3]);
      }
    #pragma unroll
    for (int kt = 0; kt < 4; ++kt) {
      unsigned u[4];
      int rb = 32*(kt>>1) + 16*(kt&1) + 4*h;
      #pragma unroll
      for (int wq = 0; wq < 4; ++wq) {
        int r = rb + 8*(wq>>1) + 2*(wq&1);
        float v0 = (n < 12) ? W3g[r*12 + n]     : 0.f;
        float v1 = (n < 12) ? W3g[(r+1)*12 + n] : 0.f;
        u[wq] = pk2(v0, v1);
      }
      w3f[kt] = mkfrag(u[0], u[1], u[2], u[3]);
    }
    // bias-extension frags: value at slot (h=0, elem 0) on BOTH operands (position-matched)
    bf16x8 bconf  = mkfrag((h == 0) ? pk2(1.f, 0.f) : 0u, 0u, 0u, 0u);
    bf16x8 w2bef0 = mkfrag((h == 0) ? pk2(b2g[n],      0.f) : 0u, 0u, 0u, 0u);
    bf16x8 w2bef1 = mkfrag((h == 0) ? pk2(b2g[32 + n], 0.f) : 0u, 0u, 0u, 0u);
    bf16x8 w3bef  = mkfrag((h == 0 && n < 12) ? pk2(b3g[n], 0.f) : 0u, 0u, 0u, 0u);

    // ---------------- main: 4 chunks of 32 rows, all register-resident ----------------
    #pragma unroll
    for (int ch = 0; ch < 4; ++ch) {
      const int row = ch * 32 + n;
      const unsigned short* xrow = xs + (p * RT + row) * XSTR;
      bf16x8 xb0 = *(const bf16x8*)(xrow + 8 * h);
      bf16x8 xb1 = *(const bf16x8*)(xrow + 16 + 8 * h);

      // mm1: H1^T = W1a^T · [X|1]^T
      f32x16 c1[2];
      #pragma unroll
      for (int mt = 0; mt < 2; ++mt) {
        c1[mt] = mfma32(w1f[mt][0], xb0, z);
        c1[mt] = mfma32(w1f[mt][1], xb1, c1[mt]);
      }
      // hop1: relu + pack contiguous C-regs (phi-ordered, zero data movement)
      bf16x8 fr1[4];
      #pragma unroll
      for (int kt = 0; kt < 4; ++kt) {
        const f32x16& cc = c1[kt >> 1];
        const int bse = 8 * (kt & 1);
        fr1[kt] = mkfrag(
          pk2(fmaxf(cc[bse+0], 0.f), fmaxf(cc[bse+1], 0.f)),
          pk2(fmaxf(cc[bse+2], 0.f), fmaxf(cc[bse+3], 0.f)),
          pk2(fmaxf(cc[bse+4], 0.f), fmaxf(cc[bse+5], 0.f)),
          pk2(fmaxf(cc[bse+6], 0.f), fmaxf(cc[bse+7], 0.f)));
      }
      // mm2 (+bias MFMA)
      f32x16 c2[2];
      c2[0] = mfma32(w2bef0, bconf, z);
      c2[1] = mfma32(w2bef1, bconf, z);
      #pragma unroll
      for (int kt = 0; kt < 4; ++kt) {
        c2[0] = mfma32(w2f[0][kt], fr1[kt], c2[0]);
        c2[1] = mfma32(w2f[1][kt], fr1[kt], c2[1]);
      }
      // hop2
      bf16x8 fr2[4];
      #pragma unroll
      for (int kt = 0; kt < 4; ++kt) {
        const f32x16& cc = c2[kt >> 1];
        const int bse = 8 * (kt & 1);
        fr2[kt] = mkfrag(
          pk2(fmaxf(cc[bse+0], 0.f), fmaxf(cc[bse+1], 0.f)),
          pk2(fmaxf(cc[bse+2], 0.f), fmaxf(cc[bse+3], 0.f)),
          pk2(fmaxf(cc[bse+4], 0.f), fmaxf(cc[bse+5], 0.f)),
          pk2(fmaxf(cc[bse+6], 0.f), fmaxf(cc[bse+7], 0.f)));
      }
      // mm3 (+bias MFMA); C rows 0..11 valid (W3 M-padded with zeros)
      f32x16 c3 = mfma32(w3bef, bconf, z);
      #pragma unroll
      for (int kt = 0; kt < 4; ++kt) c3 = mfma32(w3f[kt], fr2[kt], c3);

      // o-write: C-reg r holds feat (r&3)+8*(r>>2)+4h at col n
      unsigned k0 = pk2(c3[0], c3[1]);   // feats 4h+0, 4h+1
      unsigned k1 = pk2(c3[2], c3[3]);   // feats 4h+2, 4h+3
      unsigned short* ob = os + (((p * 2 + c) * 129 + row) * 12);
      *(ull*)(ob + 4 * h) = (ull)k0 | ((ull)k1 << 32);
      if (h == 0) {
        unsigned k2 = pk2(c3[4], c3[5]); // feats 8,9
        unsigned k3 = pk2(c3[6], c3[7]); // feats 10,11
        *(ull*)(ob + 8) = (ull)k2 | ((ull)k3 << 32);
      }
    }
    __syncthreads();

    // ---------------- residual combine ----------------
    {
      const int r = tid >> 2, pp = tid & 3;
      float sum[24], own[24], yn[24];
      #pragma unroll
      for (int k = 0; k < 24; ++k) sum[k] = 0.f;
      #pragma unroll
      for (int pp2 = 0; pp2 < 4; ++pp2)
        #pragma unroll
        for (int cc = 0; cc < 2; ++cc) {
          const ull* orow = (const ull*)(os + ((pp2 * 2 + cc) * 129 + r) * 12);
          float t[12];
          unp4(orow[0], t); unp4(orow[1], t + 4); unp4(orow[2], t + 8);
          #pragma unroll
          for (int l = 0; l < 12; ++l) sum[cc * 12 + l] += t[l];
        }
      #pragma unroll
      for (int cc = 0; cc < 2; ++cc) {
        const ull* orow = (const ull*)(os + ((pp * 2 + cc) * 129 + r) * 12);
        unp4(orow[0], own + cc * 12); unp4(orow[1], own + cc * 12 + 4); unp4(orow[2], own + cc * 12 + 8);
        const ull* yrow = (const ull*)(ys + (cc * RT + r) * 12);
        unp4(yrow[0], yn + cc * 12); unp4(yrow[1], yn + cc * 12 + 4); unp4(yrow[2], yn + cc * 12 + 8);
      }
      if (s < 2) {
        unsigned xw[12];
        #pragma unroll
        for (int j = 0; j < 12; ++j) {
          float v0 = own[2*j]   + (yn[2*j]   - sum[2*j]);
          float v1 = own[2*j+1] + (yn[2*j+1] - sum[2*j+1]);
          xw[j] = pk2(v0, v1);
        }
        u32x4* xr = (u32x4*)(xs + (pp * RT + r) * XSTR);
        u32x4 t0; t0[0]=xw[0]; t0[1]=xw[1]; t0[2]=xw[2];  t0[3]=xw[3];
        u32x4 t1; t1[0]=xw[4]; t1[1]=xw[5]; t1[2]=xw[6];  t1[3]=xw[7];
        u32x4 t2; t2[0]=xw[8]; t2[1]=xw[9]; t2[2]=xw[10]; t2[3]=xw[11];
        xr[0]=t0; xr[1]=t1; xr[2]=t2;
        __syncthreads();
      } else {
        const float ev = es[r];
        float vals[24];
        #pragma unroll
        for (int l = 0; l < 12; ++l) {
          vals[2*l]   = (own[l]      + yn[l]      - sum[l])      * ev;
          vals[2*l+1] = (own[12 + l] + yn[12 + l] - sum[12 + l]) * ev;
        }
        __syncthreads();                       // all o/y/e reads done
        float* vstg = (float*)smem;            // overlays x/o regions
        f32x4* vw = (f32x4*)(vstg + r * 96 + pp * 24);
        #pragma unroll
        for (int i = 0; i < 6; ++i) {
          f32x4 t; t[0]=vals[4*i]; t[1]=vals[4*i+1]; t[2]=vals[4*i+2]; t[3]=vals[4*i+3];
          vw[i] = t;
        }
        __syncthreads();
        const f32x4* vp = (const f32x4*)vstg;
        f32x4* og = (f32x4*)(out + r0 * 96);
        #pragma unroll
        for (int i = 0; i < 6; ++i) og[tid + 512 * i] = vp[tid + 512 * i];
      }
    }
  }
}

extern "C" void kernel_launch(void* const* d_in, const int* in_sizes, int n_in,
                              void* d_out, int out_size, void* d_ws, size_t ws_size,
                              hipStream_t stream) {
  const float* y_real = (const float*)d_in[0];
  const float* y_imag = (const float*)d_in[1];
  const float* W1 = (const float*)d_in[2];
  const float* b1 = (const float*)d_in[3];
  const float* W2 = (const float*)d_in[4];
  const float* b2 = (const float*)d_in[5];
  const float* W3 = (const float*)d_in[6];
  const float* b3 = (const float*)d_in[7];
  float* out = (float*)d_out;

  hipLaunchKernelGGL(rrsep, dim3(NB), dim3(512), 0, stream,
                     y_real, y_imag, W1, b1, W2, b2, W3, b3, out);
}

// Round 6
// 448.322 us; speedup vs baseline: 1.1491x; 1.0380x over previous
//
#include <hip/hip_runtime.h>
#include <hip/hip_bf16.h>

typedef __attribute__((ext_vector_type(8))) short bf16x8;
typedef __attribute__((ext_vector_type(4))) float f32x4;
typedef __attribute__((ext_vector_type(16))) float f32x16;
typedef __attribute__((ext_vector_type(4))) unsigned int u32x4;
typedef unsigned long long ull;

#define RT 128
#define NB (262144 / RT)
#define XSTR 40   // x row stride in bf16 elems (aug pair at 24/25, zeros 26..31)

// LDS byte offsets
#define X_OFF 0          // x: [4][128][XSTR] bf16  = 40960 B
#define O_OFF 40960      // o: [4][2][129][12] bf16 = 24768 B
#define Y_OFF 65728      // y: [2][128][12] bf16    =  6144 B
#define E_OFF 71872      // e: [128] f32            =   512 B
#define SMEM_BYTES 72384

// ROUND-6 SINGLE DELTA vs round 3 (passing): this function body only.
// 3-VALU bf16 pair pack, NO inline asm (round 4/5 proved asm cvt_pk poisons
// this kernel): round-to-nearest-ties-away via +0x8000, then one v_perm_b32
// packs the two high halves: D[15:0]=bf16(lo), D[31:16]=bf16(hi).
// Selector 0x07060302: D bytes = {src0.b3, src0.b2, src1.b3, src1.b2}.
__device__ __forceinline__ unsigned pk2(float lo, float hi) {
  union { float f; unsigned u; } a, b;
  a.f = lo; b.f = hi;
  return __builtin_amdgcn_perm(b.u + 0x8000u, a.u + 0x8000u, 0x07060302u);
}
__device__ __forceinline__ void unp4(ull v, float* d) {
  unsigned a = (unsigned)v, b = (unsigned)(v >> 32);
  union { unsigned u; float f; } x;
  x.u = a << 16;         d[0] = x.f;
  x.u = a & 0xffff0000u; d[1] = x.f;
  x.u = b << 16;         d[2] = x.f;
  x.u = b & 0xffff0000u; d[3] = x.f;
}
__device__ __forceinline__ bf16x8 mkfrag(unsigned w0, unsigned w1, unsigned w2, unsigned w3) {
  union { bf16x8 v; unsigned u[4]; } U;
  U.u[0] = w0; U.u[1] = w1; U.u[2] = w2; U.u[3] = w3;
  return U.v;
}
__device__ __forceinline__ f32x16 mfma32(bf16x8 a, bf16x8 b, f32x16 c) {
  return __builtin_amdgcn_mfma_f32_32x32x16_bf16(a, b, c, 0, 0, 0);
}

__global__ __launch_bounds__(512, 2) void rrsep(
    const float* __restrict__ y_real, const float* __restrict__ y_imag,
    const float* __restrict__ W1, const float* __restrict__ b1,
    const float* __restrict__ W2, const float* __restrict__ b2,
    const float* __restrict__ W3, const float* __restrict__ b3,
    float* __restrict__ out)
{
  __shared__ __align__(16) char smem[SMEM_BYTES];
  unsigned short* xs = (unsigned short*)(smem + X_OFF);
  unsigned short* os = (unsigned short*)(smem + O_OFF);
  unsigned short* ys = (unsigned short*)(smem + Y_OFF);
  float* es = (float*)(smem + E_OFF);

  const int tid  = (int)threadIdx.x;
  const int lane = tid & 63;
  const int w    = tid >> 6;     // wave 0..7
  const int p    = w >> 1;       // port
  const int c    = w & 1;        // channel
  const int n    = lane & 31;    // data column / weight m-lane
  const int h    = lane >> 5;    // lane half
  const long r0  = (long)blockIdx.x * RT;

  // ---------------- prologue: coalesced load, normalize, init x ----------------
  {
    float* stg = (float*)smem;   // overlays x region before its first use
    if (tid < 384) {
      ((f32x4*)stg)[tid]          = ((const f32x4*)(y_real + r0 * 12))[tid];
      ((f32x4*)(stg + 1536))[tid] = ((const f32x4*)(y_imag + r0 * 12))[tid];
    }
    __syncthreads();
    float yv[24]; float ev = 0.f, inv = 0.f;
    if (tid < RT) {
      float acc = 0.f;
      #pragma unroll
      for (int l = 0; l < 12; ++l) {
        yv[l]      = stg[tid * 12 + l];
        yv[12 + l] = stg[1536 + tid * 12 + l];
        acc += yv[l] * yv[l] + yv[12 + l] * yv[12 + l];
      }
      ev  = sqrtf(acc * (1.f / 12.f));
      inv = 1.f / (ev + 1e-8f);
    }
    __syncthreads();   // all slab reads done before x overwrites the region
    if (tid < RT) {
      es[tid] = ev;
      unsigned pkw[12];
      #pragma unroll
      for (int j = 0; j < 12; ++j) pkw[j] = pk2(yv[2*j] * inv, yv[2*j+1] * inv);
      ull* yr0 = (ull*)(ys + (0 * RT + tid) * 12);
      yr0[0] = (ull)pkw[0] | ((ull)pkw[1] << 32);
      yr0[1] = (ull)pkw[2] | ((ull)pkw[3] << 32);
      yr0[2] = (ull)pkw[4] | ((ull)pkw[5] << 32);
      ull* yr1 = (ull*)(ys + (1 * RT + tid) * 12);
      yr1[0] = (ull)pkw[6]  | ((ull)pkw[7]  << 32);
      yr1[1] = (ull)pkw[8]  | ((ull)pkw[9]  << 32);
      yr1[2] = (ull)pkw[10] | ((ull)pkw[11] << 32);
      #pragma unroll
      for (int p2 = 0; p2 < 4; ++p2) {
        u32x4* xr = (u32x4*)(xs + (p2 * RT + tid) * XSTR);
        u32x4 t0; t0[0]=pkw[0]; t0[1]=pkw[1]; t0[2]=pkw[2]; t0[3]=pkw[3];
        u32x4 t1; t1[0]=pkw[4]; t1[1]=pkw[5]; t1[2]=pkw[6]; t1[3]=pkw[7];
        u32x4 t2; t2[0]=pkw[8]; t2[1]=pkw[9]; t2[2]=pkw[10]; t2[3]=pkw[11];
        u32x4 t3; t3[0]=pk2(1.f, 0.f); t3[1]=0u; t3[2]=0u; t3[3]=0u;  // aug x[24]=1, pad 25..31=0
        xr[0]=t0; xr[1]=t1; xr[2]=t2; xr[3]=t3;
      }
    }
    __syncthreads();
  }

  f32x16 z;
  #pragma unroll
  for (int i = 0; i < 16; ++i) z[i] = 0.f;

  #pragma unroll 1
  for (int s = 0; s < 3; ++s) {
    const int pc = (s * 4 + p) * 2 + c;
    const float* W1g = W1 + pc * 24 * 64;
    const float* b1g = b1 + pc * 64;
    const float* W2g = W2 + pc * 64 * 64;
    const float* b2g = b2 + pc * 64;
    const float* W3g = W3 + pc * 64 * 12;
    const float* b3g = b3 + pc * 12;

    // ---- mm1 A-frags: elem j (half h) <-> k = 16kt+8h+j; A[m][k] = W1[k][m], k24 = b1 ----
    bf16x8 w1f[2][2];
    #pragma unroll
    for (int mt = 0; mt < 2; ++mt)
      #pragma unroll
      for (int kt = 0; kt < 2; ++kt) {
        unsigned u[4];
        #pragma unroll
        for (int wq = 0; wq < 4; ++wq) {
          int k0 = 16*kt + 8*h + 2*wq, k1 = k0 + 1;
          int m  = 32*mt + n;
          float v0 = (k0 < 24) ? W1g[k0*64 + m] : ((k0 == 24) ? b1g[m] : 0.f);
          float v1 = (k1 < 24) ? W1g[k1*64 + m] : 0.f;   // k1 odd, never the aug slot
          u[wq] = pk2(v0, v1);
        }
        w1f[mt][kt] = mkfrag(u[0], u[1], u[2], u[3]);
      }

    // ---- mm2/mm3 A-frags with phi-permuted rows so the hop is register-contiguous ----
    // phi(kt,h,j) = 32*(kt>>1) + 16*(kt&1) + 8*(j>>2) + 4h + (j&3)
    //  == the feature held by C-reg c[kt>>1][8*(kt&1)+j] (C/D layout, HW-verified)
    bf16x8 w2f[2][4], w3f[4];
    #pragma unroll
    for (int mt = 0; mt < 2; ++mt)
      #pragma unroll
      for (int kt = 0; kt < 4; ++kt) {
        unsigned u[4];
        int m  = 32*mt + n;
        int rb = 32*(kt>>1) + 16*(kt&1) + 4*h;
        #pragma unroll
        for (int wq = 0; wq < 4; ++wq) {
          int r = rb + 8*(wq>>1) + 2*(wq&1);         // rows for elems 2wq, 2wq+1
          u[wq] = pk2(W2g[r*64 + m], W2g[(r+1)*64 + m]);
        }
        w2f[mt][kt] = mkfrag(u[0], u[1], u[2], u[3]);
      }
    #pragma unroll
    for (int kt = 0; kt < 4; ++kt) {
      unsigned u[4];
      int rb = 32*(kt>>1) + 16*(kt&1) + 4*h;
      #pragma unroll
      for (int wq = 0; wq < 4; ++wq) {
        int r = rb + 8*(wq>>1) + 2*(wq&1);
        float v0 = (n < 12) ? W3g[r*12 + n]     : 0.f;
        float v1 = (n < 12) ? W3g[(r+1)*12 + n] : 0.f;
        u[wq] = pk2(v0, v1);
      }
      w3f[kt] = mkfrag(u[0], u[1], u[2], u[3]);
    }
    // bias-extension frags: value at slot (h=0, elem 0) on BOTH operands (position-matched)
    bf16x8 bconf  = mkfrag((h == 0) ? pk2(1.f, 0.f) : 0u, 0u, 0u, 0u);
    bf16x8 w2bef0 = mkfrag((h == 0) ? pk2(b2g[n],      0.f) : 0u, 0u, 0u, 0u);
    bf16x8 w2bef1 = mkfrag((h == 0) ? pk2(b2g[32 + n], 0.f) : 0u, 0u, 0u, 0u);
    bf16x8 w3bef  = mkfrag((h == 0 && n < 12) ? pk2(b3g[n], 0.f) : 0u, 0u, 0u, 0u);

    // ---------------- main: 4 chunks of 32 rows, all register-resident ----------------
    #pragma unroll
    for (int ch = 0; ch < 4; ++ch) {
      const int row = ch * 32 + n;
      const unsigned short* xrow = xs + (p * RT + row) * XSTR;
      bf16x8 xb0 = *(const bf16x8*)(xrow + 8 * h);
      bf16x8 xb1 = *(const bf16x8*)(xrow + 16 + 8 * h);

      // mm1: H1^T = W1a^T · [X|1]^T
      f32x16 c1[2];
      #pragma unroll
      for (int mt = 0; mt < 2; ++mt) {
        c1[mt] = mfma32(w1f[mt][0], xb0, z);
        c1[mt] = mfma32(w1f[mt][1], xb1, c1[mt]);
      }
      // hop1: relu + pack contiguous C-regs (phi-ordered, zero data movement)
      bf16x8 fr1[4];
      #pragma unroll
      for (int kt = 0; kt < 4; ++kt) {
        const f32x16& cc = c1[kt >> 1];
        const int bse = 8 * (kt & 1);
        fr1[kt] = mkfrag(
          pk2(fmaxf(cc[bse+0], 0.f), fmaxf(cc[bse+1], 0.f)),
          pk2(fmaxf(cc[bse+2], 0.f), fmaxf(cc[bse+3], 0.f)),
          pk2(fmaxf(cc[bse+4], 0.f), fmaxf(cc[bse+5], 0.f)),
          pk2(fmaxf(cc[bse+6], 0.f), fmaxf(cc[bse+7], 0.f)));
      }
      // mm2 (+bias MFMA)
      f32x16 c2[2];
      c2[0] = mfma32(w2bef0, bconf, z);
      c2[1] = mfma32(w2bef1, bconf, z);
      #pragma unroll
      for (int kt = 0; kt < 4; ++kt) {
        c2[0] = mfma32(w2f[0][kt], fr1[kt], c2[0]);
        c2[1] = mfma32(w2f[1][kt], fr1[kt], c2[1]);
      }
      // hop2
      bf16x8 fr2[4];
      #pragma unroll
      for (int kt = 0; kt < 4; ++kt) {
        const f32x16& cc = c2[kt >> 1];
        const int bse = 8 * (kt & 1);
        fr2[kt] = mkfrag(
          pk2(fmaxf(cc[bse+0], 0.f), fmaxf(cc[bse+1], 0.f)),
          pk2(fmaxf(cc[bse+2], 0.f), fmaxf(cc[bse+3], 0.f)),
          pk2(fmaxf(cc[bse+4], 0.f), fmaxf(cc[bse+5], 0.f)),
          pk2(fmaxf(cc[bse+6], 0.f), fmaxf(cc[bse+7], 0.f)));
      }
      // mm3 (+bias MFMA); C rows 0..11 valid (W3 M-padded with zeros)
      f32x16 c3 = mfma32(w3bef, bconf, z);
      #pragma unroll
      for (int kt = 0; kt < 4; ++kt) c3 = mfma32(w3f[kt], fr2[kt], c3);

      // o-write: C-reg r holds feat (r&3)+8*(r>>2)+4h at col n
      unsigned k0 = pk2(c3[0], c3[1]);   // feats 4h+0, 4h+1
      unsigned k1 = pk2(c3[2], c3[3]);   // feats 4h+2, 4h+3
      unsigned short* ob = os + (((p * 2 + c) * 129 + row) * 12);
      *(ull*)(ob + 4 * h) = (ull)k0 | ((ull)k1 << 32);
      if (h == 0) {
        unsigned k2 = pk2(c3[4], c3[5]); // feats 8,9
        unsigned k3 = pk2(c3[6], c3[7]); // feats 10,11
        *(ull*)(ob + 8) = (ull)k2 | ((ull)k3 << 32);
      }
    }
    __syncthreads();

    // ---------------- residual combine ----------------
    {
      const int r = tid >> 2, pp = tid & 3;
      float sum[24], own[24], yn[24];
      #pragma unroll
      for (int k = 0; k < 24; ++k) sum[k] = 0.f;
      #pragma unroll
      for (int pp2 = 0; pp2 < 4; ++pp2)
        #pragma unroll
        for (int cc = 0; cc < 2; ++cc) {
          const ull* orow = (const ull*)(os + ((pp2 * 2 + cc) * 129 + r) * 12);
          float t[12];
          unp4(orow[0], t); unp4(orow[1], t + 4); unp4(orow[2], t + 8);
          #pragma unroll
          for (int l = 0; l < 12; ++l) sum[cc * 12 + l] += t[l];
        }
      #pragma unroll
      for (int cc = 0; cc < 2; ++cc) {
        const ull* orow = (const ull*)(os + ((pp * 2 + cc) * 129 + r) * 12);
        unp4(orow[0], own + cc * 12); unp4(orow[1], own + cc * 12 + 4); unp4(orow[2], own + cc * 12 + 8);
        const ull* yrow = (const ull*)(ys + (cc * RT + r) * 12);
        unp4(yrow[0], yn + cc * 12); unp4(yrow[1], yn + cc * 12 + 4); unp4(yrow[2], yn + cc * 12 + 8);
      }
      if (s < 2) {
        unsigned xw[12];
        #pragma unroll
        for (int j = 0; j < 12; ++j) {
          float v0 = own[2*j]   + (yn[2*j]   - sum[2*j]);
          float v1 = own[2*j+1] + (yn[2*j+1] - sum[2*j+1]);
          xw[j] = pk2(v0, v1);
        }
        u32x4* xr = (u32x4*)(xs + (pp * RT + r) * XSTR);
        u32x4 t0; t0[0]=xw[0]; t0[1]=xw[1]; t0[2]=xw[2];  t0[3]=xw[3];
        u32x4 t1; t1[0]=xw[4]; t1[1]=xw[5]; t1[2]=xw[6];  t1[3]=xw[7];
        u32x4 t2; t2[0]=xw[8]; t2[1]=xw[9]; t2[2]=xw[10]; t2[3]=xw[11];
        xr[0]=t0; xr[1]=t1; xr[2]=t2;
        __syncthreads();
      } else {
        const float ev = es[r];
        float vals[24];
        #pragma unroll
        for (int l = 0; l < 12; ++l) {
          vals[2*l]   = (own[l]      + yn[l]      - sum[l])      * ev;
          vals[2*l+1] = (own[12 + l] + yn[12 + l] - sum[12 + l]) * ev;
        }
        __syncthreads();                       // all o/y/e reads done
        float* vstg = (float*)smem;            // overlays x/o regions
        f32x4* vw = (f32x4*)(vstg + r * 96 + pp * 24);
        #pragma unroll
        for (int i = 0; i < 6; ++i) {
          f32x4 t; t[0]=vals[4*i]; t[1]=vals[4*i+1]; t[2]=vals[4*i+2]; t[3]=vals[4*i+3];
          vw[i] = t;
        }
        __syncthreads();
        const f32x4* vp = (const f32x4*)vstg;
        f32x4* og = (f32x4*)(out + r0 * 96);
        #pragma unroll
        for (int i = 0; i < 6; ++i) og[tid + 512 * i] = vp[tid + 512 * i];
      }
    }
  }
}

extern "C" void kernel_launch(void* const* d_in, const int* in_sizes, int n_in,
                              void* d_out, int out_size, void* d_ws, size_t ws_size,
                              hipStream_t stream) {
  const float* y_real = (const float*)d_in[0];
  const float* y_imag = (const float*)d_in[1];
  const float* W1 = (const float*)d_in[2];
  const float* b1 = (const float*)d_in[3];
  const float* W2 = (const float*)d_in[4];
  const float* b2 = (const float*)d_in[5];
  const float* W3 = (const float*)d_in[6];
  const float* b3 = (const float*)d_in[7];
  float* out = (float*)d_out;

  hipLaunchKernelGGL(rrsep, dim3(NB), dim3(512), 0, stream,
                     y_real, y_imag, W1, b1, W2, b2, W3, b3, out);
}